// Round 1
// baseline (2252.164 us; speedup 1.0000x reference)
//
#include <hip/hip_runtime.h>
#include <cstdint>
#include <cfloat>
#include <cstddef>

#define MAXK 128

// ---------------------------------------------------------------------------
// Encode GEMM: z_pre[b, f] = sum_d (x[b,d] - b_dec[d]) * W_enc[f,d] + b_enc[f]
// A = x [B, D] row-major, B = W_enc [F, D] row-major (NT gemm, K = D).
// 128x128 tile, BK=16, 256 threads, 8x8 micro-tile split as 4x4 quads at
// {tm, tm+64} x {tn, tn+64} so LDS fragment reads are <=2-way conflicted.
// ---------------------------------------------------------------------------
__global__ __launch_bounds__(256, 2)
void encode_gemm(const float* __restrict__ x, const float* __restrict__ Wenc,
                 const float* __restrict__ b_enc, const float* __restrict__ b_dec,
                 float* __restrict__ z_pre, int D, int F)
{
    constexpr int BM = 128, BN = 128, BK = 16, PAD = 4;
    __shared__ float As[BK][BM + PAD];
    __shared__ float Bs[BK][BN + PAD];

    const int tid = threadIdx.x;
    const int bm  = blockIdx.x * BM;
    const int bn  = blockIdx.y * BN;

    // staging map: 512 float4 per tile; thread handles rows lrow and lrow+64
    const int lrow = tid >> 2;         // 0..63
    const int lcol = (tid & 3) << 2;   // 0,4,8,12

    const float* pA0 = x    + (size_t)(bm + lrow)      * D + lcol;
    const float* pA1 = x    + (size_t)(bm + lrow + 64) * D + lcol;
    const float* pB0 = Wenc + (size_t)(bn + lrow)      * D + lcol;
    const float* pB1 = Wenc + (size_t)(bn + lrow + 64) * D + lcol;

    float acc[8][8];
    #pragma unroll
    for (int i = 0; i < 8; ++i)
        #pragma unroll
        for (int j = 0; j < 8; ++j) acc[i][j] = 0.f;

    const int tm = (tid >> 4) << 2;   // 0..60
    const int tn = (tid & 15) << 2;   // 0..60

    for (int k0 = 0; k0 < D; k0 += BK) {
        float4 a0 = *(const float4*)(pA0 + k0);
        float4 a1 = *(const float4*)(pA1 + k0);
        float4 w0 = *(const float4*)(pB0 + k0);
        float4 w1 = *(const float4*)(pB1 + k0);
        float4 bd = *(const float4*)(b_dec + k0 + lcol);
        a0.x -= bd.x; a0.y -= bd.y; a0.z -= bd.z; a0.w -= bd.w;
        a1.x -= bd.x; a1.y -= bd.y; a1.z -= bd.z; a1.w -= bd.w;

        As[lcol + 0][lrow]      = a0.x;
        As[lcol + 1][lrow]      = a0.y;
        As[lcol + 2][lrow]      = a0.z;
        As[lcol + 3][lrow]      = a0.w;
        As[lcol + 0][lrow + 64] = a1.x;
        As[lcol + 1][lrow + 64] = a1.y;
        As[lcol + 2][lrow + 64] = a1.z;
        As[lcol + 3][lrow + 64] = a1.w;

        Bs[lcol + 0][lrow]      = w0.x;
        Bs[lcol + 1][lrow]      = w0.y;
        Bs[lcol + 2][lrow]      = w0.z;
        Bs[lcol + 3][lrow]      = w0.w;
        Bs[lcol + 0][lrow + 64] = w1.x;
        Bs[lcol + 1][lrow + 64] = w1.y;
        Bs[lcol + 2][lrow + 64] = w1.z;
        Bs[lcol + 3][lrow + 64] = w1.w;

        __syncthreads();

        #pragma unroll
        for (int kk = 0; kk < BK; ++kk) {
            float4 aA = *(const float4*)&As[kk][tm];
            float4 aB = *(const float4*)&As[kk][tm + 64];
            float4 bA = *(const float4*)&Bs[kk][tn];
            float4 bB = *(const float4*)&Bs[kk][tn + 64];
            float av[8] = {aA.x, aA.y, aA.z, aA.w, aB.x, aB.y, aB.z, aB.w};
            float bv[8] = {bA.x, bA.y, bA.z, bA.w, bB.x, bB.y, bB.z, bB.w};
            #pragma unroll
            for (int i = 0; i < 8; ++i)
                #pragma unroll
                for (int j = 0; j < 8; ++j)
                    acc[i][j] = fmaf(av[i], bv[j], acc[i][j]);
        }
        __syncthreads();
    }

    // epilogue: + b_enc, write z_pre
    #pragma unroll
    for (int ii = 0; ii < 2; ++ii) {
        #pragma unroll
        for (int i = 0; i < 4; ++i) {
            const int r = bm + tm + ii * 64 + i;
            float* dst = z_pre + (size_t)r * F + bn;
            #pragma unroll
            for (int jj = 0; jj < 2; ++jj) {
                const int c = tn + jj * 64;
                float4 v;
                v.x = acc[ii * 4 + i][jj * 4 + 0] + b_enc[bn + c + 0];
                v.y = acc[ii * 4 + i][jj * 4 + 1] + b_enc[bn + c + 1];
                v.z = acc[ii * 4 + i][jj * 4 + 2] + b_enc[bn + c + 2];
                v.w = acc[ii * 4 + i][jj * 4 + 3] + b_enc[bn + c + 3];
                *(float4*)(dst + c) = v;
            }
        }
    }
}

// ---------------------------------------------------------------------------
// Monotonic uint key for float ordering (no NaNs expected)
// ---------------------------------------------------------------------------
__device__ __forceinline__ unsigned fkey(float f)
{
    unsigned u = __float_as_uint(f);
    return u ^ ((unsigned)((int)u >> 31) | 0x80000000u);
}

// ---------------------------------------------------------------------------
// Per-row top-k via 4-pass MSB radix select. One block (256 thr) per row.
// Writes dense z (zeros + relu(topk)) and a compact (val, idx) list to ws.
// Tie-break at the threshold value: lowest index first (matches lax.top_k).
// ---------------------------------------------------------------------------
template <int NVEC>
__global__ __launch_bounds__(256)
void topk_kernel(const float* __restrict__ z_pre, float* __restrict__ z,
                 float* __restrict__ ws_vals, int* __restrict__ ws_idx,
                 const int* __restrict__ k_ptr, int F)
{
    const int row = blockIdx.x;
    const int t   = threadIdx.x;
    const int k   = *k_ptr;
    const int nv4 = F >> 2;

    const float4* src = (const float4*)(z_pre + (size_t)row * F);
    float4 vals[NVEC];
    #pragma unroll
    for (int i = 0; i < NVEC; ++i) {
        const int p = t + 256 * i;
        if (p < nv4) vals[i] = src[p];
        else         vals[i] = make_float4(-FLT_MAX, -FLT_MAX, -FLT_MAX, -FLT_MAX);
    }

    __shared__ int hist[256];
    __shared__ int suffix[256];
    __shared__ int s_bin;

    unsigned prefix = 0;
    int rem = k;

    for (int pass = 0; pass < 4; ++pass) {
        const int shift = 24 - 8 * pass;
        hist[t] = 0;
        __syncthreads();

        #pragma unroll
        for (int i = 0; i < NVEC; ++i) {
            const float* vv = (const float*)&vals[i];
            #pragma unroll
            for (int j = 0; j < 4; ++j) {
                const unsigned key = fkey(vv[j]);
                const bool inb = (pass == 0) || ((key >> (shift + 8)) == prefix);
                if (inb) atomicAdd(&hist[(key >> shift) & 255], 1);
            }
        }
        __syncthreads();

        suffix[t] = hist[t];
        __syncthreads();
        #pragma unroll
        for (int off = 1; off < 256; off <<= 1) {
            const int add = (t + off < 256) ? suffix[t + off] : 0;
            __syncthreads();
            suffix[t] += add;
            __syncthreads();
        }

        const int sfx = suffix[t];
        const int nxt = (t < 255) ? suffix[t + 1] : 0;
        if (sfx >= rem && nxt < rem) s_bin = t;
        __syncthreads();
        const int b = s_bin;
        const int above = (b < 255) ? suffix[b + 1] : 0;
        rem -= above;
        prefix = (prefix << 8) | (unsigned)b;
        __syncthreads();
    }

    const unsigned T = prefix;   // exact key of the k-th largest value

    // tie handling: pick the `rem` lowest indices among keys == T
    __shared__ int eq_cnt;
    __shared__ int eq_list[256];
    __shared__ int s_cut;
    __shared__ int out_cnt;
    if (t == 0) { eq_cnt = 0; out_cnt = 0; }
    __syncthreads();

    #pragma unroll
    for (int i = 0; i < NVEC; ++i) {
        const float* vv = (const float*)&vals[i];
        #pragma unroll
        for (int j = 0; j < 4; ++j) {
            if (fkey(vv[j]) == T) {
                const int s = atomicAdd(&eq_cnt, 1);
                if (s < 256) eq_list[s] = (t + 256 * i) * 4 + j;
            }
        }
    }
    __syncthreads();

    if (t == 0) {
        const int n = min(eq_cnt, 256);
        int cut;
        if (rem >= n) {
            cut = 0x7FFFFFFF;  // take all equals
        } else {
            int last = -1;
            for (int it = 0; it < rem; ++it) {
                int best = 0x7FFFFFFF;
                for (int j2 = 0; j2 < n; ++j2) {
                    const int p = eq_list[j2];
                    if (p > last && p < best) best = p;
                }
                last = best;
            }
            cut = last;
        }
        s_cut = cut;
    }
    __syncthreads();
    const int cut = s_cut;

    float4* dstz = (float4*)(z + (size_t)row * F);
    float*  wv   = ws_vals + (size_t)row * MAXK;
    int*    wi   = ws_idx  + (size_t)row * MAXK;

    #pragma unroll
    for (int i = 0; i < NVEC; ++i) {
        const int p4 = t + 256 * i;
        if (p4 < nv4) {
            const float* vv = (const float*)&vals[i];
            float4 outv;
            float* ov = (float*)&outv;
            #pragma unroll
            for (int j = 0; j < 4; ++j) {
                const int pos = p4 * 4 + j;
                const unsigned key = fkey(vv[j]);
                const bool sel = (key > T) || (key == T && pos <= cut);
                const float zv = sel ? fmaxf(vv[j], 0.f) : 0.f;
                ov[j] = zv;
                if (sel) {
                    const int s = atomicAdd(&out_cnt, 1);
                    if (s < MAXK) { wv[s] = zv; wi[s] = pos; }
                }
            }
            dstz[p4] = outv;
        }
    }
}

// ---------------------------------------------------------------------------
// Transpose W_dec [R=D, C=F] -> W_decT [F, D] so decode gathers are coalesced
// ---------------------------------------------------------------------------
__global__ __launch_bounds__(256)
void transpose_kernel(const float* __restrict__ in, float* __restrict__ out,
                      int R, int C)
{
    __shared__ float tile[32][33];
    const int c0 = blockIdx.x * 32;
    const int r0 = blockIdx.y * 32;
    const int tx = threadIdx.x & 31;
    const int ty = threadIdx.x >> 5;  // 0..7

    #pragma unroll
    for (int i = ty; i < 32; i += 8) {
        const int r = r0 + i, c = c0 + tx;
        tile[i][tx] = (r < R && c < C) ? in[(size_t)r * C + c] : 0.f;
    }
    __syncthreads();
    #pragma unroll
    for (int i = ty; i < 32; i += 8) {
        const int c = c0 + i, r = r0 + tx;
        if (c < C && r < R) out[(size_t)c * R + r] = tile[tx][i];
    }
}

// ---------------------------------------------------------------------------
// Sparse decode: x_hat[b, :] = b_dec + sum_j val_j * W_decT[idx_j, :]
// One block per row; thread t owns d = 4t..4t+3 (strided loop for D > 1024).
// ---------------------------------------------------------------------------
__global__ __launch_bounds__(256)
void decode_kernel(const float* __restrict__ WdT, const float* __restrict__ wvals,
                   const int* __restrict__ widx, const float* __restrict__ b_dec,
                   float* __restrict__ x_hat, const int* __restrict__ k_ptr, int D)
{
    const int row = blockIdx.x;
    const int t   = threadIdx.x;
    int k = *k_ptr;
    if (k > MAXK) k = MAXK;

    const float* wv = wvals + (size_t)row * MAXK;
    const int*   wi = widx  + (size_t)row * MAXK;

    for (int d0 = t * 4; d0 < D; d0 += 1024) {
        float4 acc = *(const float4*)(b_dec + d0);
        for (int j = 0; j < k; ++j) {
            const float v = wv[j];
            const int   f = wi[j];
            const float4 w = *(const float4*)(WdT + (size_t)f * D + d0);
            acc.x = fmaf(v, w.x, acc.x);
            acc.y = fmaf(v, w.y, acc.y);
            acc.z = fmaf(v, w.z, acc.z);
            acc.w = fmaf(v, w.w, acc.w);
        }
        *(float4*)(x_hat + (size_t)row * D + d0) = acc;
    }
}

// ---------------------------------------------------------------------------
extern "C" void kernel_launch(void* const* d_in, const int* in_sizes, int n_in,
                              void* d_out, int out_size, void* d_ws, size_t ws_size,
                              hipStream_t stream)
{
    const float* x     = (const float*)d_in[0];
    const float* W_enc = (const float*)d_in[1];
    const float* b_enc = (const float*)d_in[2];
    const float* W_dec = (const float*)d_in[3];
    const float* b_dec = (const float*)d_in[4];
    const int*   k_ptr = (const int*)d_in[5];

    const int F = in_sizes[2];            // b_enc size
    const int D = in_sizes[4];            // b_dec size
    const int B = in_sizes[0] / D;        // x is B*D

    float* x_hat = (float*)d_out;
    float* z     = x_hat + (size_t)B * D;
    float* z_pre = z + (size_t)B * F;

    // workspace layout: W_decT [F*D] | vals [B*MAXK] | idx [B*MAXK]
    float* WdT = (float*)d_ws;
    float* wv  = WdT + (size_t)F * D;
    int*   wi  = (int*)(wv + (size_t)B * MAXK);

    encode_gemm<<<dim3(B / 128, F / 128), 256, 0, stream>>>(
        x, W_enc, b_enc, b_dec, z_pre, D, F);

    transpose_kernel<<<dim3((F + 31) / 32, (D + 31) / 32), 256, 0, stream>>>(
        W_dec, WdT, D, F);

    const int nv4  = F / 4;
    const int nvec = (nv4 + 255) / 256;
    if (nvec <= 4)
        topk_kernel<4><<<B, 256, 0, stream>>>(z_pre, z, wv, wi, k_ptr, F);
    else if (nvec <= 8)
        topk_kernel<8><<<B, 256, 0, stream>>>(z_pre, z, wv, wi, k_ptr, F);
    else if (nvec <= 16)
        topk_kernel<16><<<B, 256, 0, stream>>>(z_pre, z, wv, wi, k_ptr, F);
    else
        topk_kernel<32><<<B, 256, 0, stream>>>(z_pre, z, wv, wi, k_ptr, F);

    decode_kernel<<<B, 256, 0, stream>>>(WdT, wv, wi, b_dec, x_hat, k_ptr, D);
}

// Round 2
// 1517.014 us; speedup vs baseline: 1.4846x; 1.4846x over previous
//
#include <hip/hip_runtime.h>
#include <cstdint>
#include <cfloat>
#include <cstddef>

#define MAXK 128

typedef __attribute__((ext_vector_type(8))) short bf16x8;
typedef __attribute__((ext_vector_type(4))) float f32x4;

// ---------------------------------------------------------------------------
// split 8 fp32 -> hi-bf16 x8 (uint4) + lo-bf16 x8 (uint4)
// hi = truncate-to-bf16 (top 16 bits), lo = bf16(v - hi). |err| ~ 2^-16 rel.
// ---------------------------------------------------------------------------
__device__ __forceinline__ void split8(const float4& v0, const float4& v1,
                                       uint4& hp, uint4& lp)
{
    const float* v = (const float*)&v0;  // v0,v1 adjacent on stack is not
    float vv[8] = {v0.x, v0.y, v0.z, v0.w, v1.x, v1.y, v1.z, v1.w};
    unsigned h[8], l[8];
    #pragma unroll
    for (int i = 0; i < 8; ++i) {
        unsigned u  = __float_as_uint(vv[i]);
        unsigned hb = u & 0xFFFF0000u;
        float lf    = vv[i] - __uint_as_float(hb);
        h[i] = u;
        l[i] = __float_as_uint(lf);
    }
    hp.x = (h[0] >> 16) | (h[1] & 0xFFFF0000u);
    hp.y = (h[2] >> 16) | (h[3] & 0xFFFF0000u);
    hp.z = (h[4] >> 16) | (h[5] & 0xFFFF0000u);
    hp.w = (h[6] >> 16) | (h[7] & 0xFFFF0000u);
    lp.x = (l[0] >> 16) | (l[1] & 0xFFFF0000u);
    lp.y = (l[2] >> 16) | (l[3] & 0xFFFF0000u);
    lp.z = (l[4] >> 16) | (l[5] & 0xFFFF0000u);
    lp.w = (l[6] >> 16) | (l[7] & 0xFFFF0000u);
    (void)v;
}

// ---------------------------------------------------------------------------
// Encode GEMM via split-bf16 MFMA (3 products, fp32 accumulate):
// z_pre[b,f] = sum_d (x[b,d]-b_dec[d])*W_enc[f,d] + b_enc[f]
// Block tile 128(M) x 256(N), BK=32, 256 thr = 4 waves (2x2), wave 64x128.
// LDS chunk swizzle: chunk(row,kc) stored at phys kc' = (kc + (row>>1)) & 3;
// fragment ds_read_b128 then lands 2-way-per-bank (free).
// ---------------------------------------------------------------------------
__global__ __launch_bounds__(256, 2)
void encode_gemm_bf16x3(const float* __restrict__ x, const float* __restrict__ Wenc,
                        const float* __restrict__ b_enc, const float* __restrict__ b_dec,
                        float* __restrict__ z_pre, int D, int F)
{
    constexpr int BM = 128, BN = 256, BK = 32;
    __shared__ ushort AsHi[BM * BK];   //  8 KB
    __shared__ ushort AsLo[BM * BK];   //  8 KB
    __shared__ ushort BsHi[BN * BK];   // 16 KB
    __shared__ ushort BsLo[BN * BK];   // 16 KB

    const int tid = threadIdx.x;
    const int bm  = blockIdx.y * BM;
    const int bn  = blockIdx.x * BN;

    const int lane = tid & 63;
    const int w    = tid >> 6;
    const int wm   = (w >> 1) * 64;
    const int wn   = (w & 1) * 128;
    const int fr   = lane & 15;
    const int q    = lane >> 4;

    // fragment LDS offsets (ushort units), k0-invariant
    int aoff[4], boff[8];
    #pragma unroll
    for (int mi = 0; mi < 4; ++mi) {
        const int r = wm + mi * 16 + fr;
        aoff[mi] = r * 32 + (((q + (r >> 1)) & 3) * 8);
    }
    #pragma unroll
    for (int ni = 0; ni < 8; ++ni) {
        const int r = wn + ni * 16 + fr;
        boff[ni] = r * 32 + (((q + (r >> 1)) & 3) * 8);
    }

    f32x4 acc[4][8];
    #pragma unroll
    for (int mi = 0; mi < 4; ++mi)
        #pragma unroll
        for (int ni = 0; ni < 8; ++ni)
            acc[mi][ni] = (f32x4){0.f, 0.f, 0.f, 0.f};

    for (int k0 = 0; k0 < D; k0 += BK) {
        // ---- stage A (x - b_dec, split): 512 chunk-tasks, 2 per thread ----
        #pragma unroll
        for (int j = 0; j < 2; ++j) {
            const int task = tid + 256 * j;
            const int row = task >> 2, kc = task & 3;
            const float* src = x + (size_t)(bm + row) * D + k0 + kc * 8;
            float4 v0 = *(const float4*)(src);
            float4 v1 = *(const float4*)(src + 4);
            const float* bd = b_dec + k0 + kc * 8;
            float4 d0 = *(const float4*)(bd);
            float4 d1 = *(const float4*)(bd + 4);
            v0.x -= d0.x; v0.y -= d0.y; v0.z -= d0.z; v0.w -= d0.w;
            v1.x -= d1.x; v1.y -= d1.y; v1.z -= d1.z; v1.w -= d1.w;
            uint4 hp, lp;
            split8(v0, v1, hp, lp);
            const int off = row * 32 + (((kc + (row >> 1)) & 3) * 8);
            *(uint4*)&AsHi[off] = hp;
            *(uint4*)&AsLo[off] = lp;
        }
        // ---- stage B (W_enc, split): 1024 chunk-tasks, 4 per thread ----
        #pragma unroll
        for (int j = 0; j < 4; ++j) {
            const int task = tid + 256 * j;
            const int row = task >> 2, kc = task & 3;
            const float* src = Wenc + (size_t)(bn + row) * D + k0 + kc * 8;
            float4 v0 = *(const float4*)(src);
            float4 v1 = *(const float4*)(src + 4);
            uint4 hp, lp;
            split8(v0, v1, hp, lp);
            const int off = row * 32 + (((kc + (row >> 1)) & 3) * 8);
            *(uint4*)&BsHi[off] = hp;
            *(uint4*)&BsLo[off] = lp;
        }
        __syncthreads();

        // ---- compute: 4x8 tiles x 3 MFMAs ----
        bf16x8 ahi[4], alo[4];
        #pragma unroll
        for (int mi = 0; mi < 4; ++mi) {
            ahi[mi] = *(const bf16x8*)&AsHi[aoff[mi]];
            alo[mi] = *(const bf16x8*)&AsLo[aoff[mi]];
        }
        #pragma unroll
        for (int ni = 0; ni < 8; ++ni) {
            bf16x8 bhi = *(const bf16x8*)&BsHi[boff[ni]];
            bf16x8 blo = *(const bf16x8*)&BsLo[boff[ni]];
            #pragma unroll
            for (int mi = 0; mi < 4; ++mi) {
                acc[mi][ni] = __builtin_amdgcn_mfma_f32_16x16x32_bf16(alo[mi], bhi, acc[mi][ni], 0, 0, 0);
                acc[mi][ni] = __builtin_amdgcn_mfma_f32_16x16x32_bf16(ahi[mi], blo, acc[mi][ni], 0, 0, 0);
                acc[mi][ni] = __builtin_amdgcn_mfma_f32_16x16x32_bf16(ahi[mi], bhi, acc[mi][ni], 0, 0, 0);
            }
        }
        __syncthreads();
    }

    // ---- epilogue: +b_enc, store (C/D map: row = q*4+r, col = fr) ----
    #pragma unroll
    for (int ni = 0; ni < 8; ++ni) {
        const int col = bn + wn + ni * 16 + fr;
        const float be = b_enc[col];
        #pragma unroll
        for (int mi = 0; mi < 4; ++mi) {
            const int rbase = bm + wm + mi * 16 + q * 4;
            float* dst = z_pre + (size_t)rbase * F + col;
            #pragma unroll
            for (int r = 0; r < 4; ++r)
                dst[(size_t)r * F] = acc[mi][ni][r] + be;
        }
    }
}

// ---------------------------------------------------------------------------
// Monotonic uint key for float ordering
// ---------------------------------------------------------------------------
__device__ __forceinline__ unsigned fkey(float f)
{
    unsigned u = __float_as_uint(f);
    return u ^ ((unsigned)((int)u >> 31) | 0x80000000u);
}
__device__ __forceinline__ float finv(unsigned k)
{
    unsigned u = (k & 0x80000000u) ? (k ^ 0x80000000u) : ~k;
    return __uint_as_float(u);
}

// ---------------------------------------------------------------------------
// Per-row top-k on approx z_pre + exact fp32 recompute of the +-delta
// boundary window (robust to the ~3e-5 split-bf16 error).
// ---------------------------------------------------------------------------
template <int NVEC>
__global__ __launch_bounds__(256)
void topk_kernel(const float* __restrict__ z_pre, float* __restrict__ z,
                 float* __restrict__ ws_vals, int* __restrict__ ws_idx,
                 const int* __restrict__ k_ptr,
                 const float* __restrict__ x, const float* __restrict__ Wenc,
                 const float* __restrict__ b_enc, const float* __restrict__ b_dec,
                 int F, int D)
{
    const int row = blockIdx.x;
    const int t   = threadIdx.x;
    const int k   = *k_ptr;
    const int nv4 = F >> 2;

    const float4* src = (const float4*)(z_pre + (size_t)row * F);
    float4 vals[NVEC];
    #pragma unroll
    for (int i = 0; i < NVEC; ++i) {
        const int p = t + 256 * i;
        if (p < nv4) vals[i] = src[p];
        else         vals[i] = make_float4(-FLT_MAX, -FLT_MAX, -FLT_MAX, -FLT_MAX);
    }

    __shared__ int hist[256];
    __shared__ int suffix[256];
    __shared__ int s_bin;
    __shared__ int c_hi_s, n_c_s, out_cnt;
    __shared__ int cand_idx[128];
    __shared__ float cand_val[128];
    __shared__ unsigned char cand_sel[128];

    unsigned prefix = 0;
    int rem = k;

    for (int pass = 0; pass < 4; ++pass) {
        const int shift = 24 - 8 * pass;
        hist[t] = 0;
        __syncthreads();
        #pragma unroll
        for (int i = 0; i < NVEC; ++i) {
            const float* vv = (const float*)&vals[i];
            #pragma unroll
            for (int j = 0; j < 4; ++j) {
                const unsigned key = fkey(vv[j]);
                const bool inb = (pass == 0) || ((key >> (shift + 8)) == prefix);
                if (inb) atomicAdd(&hist[(key >> shift) & 255], 1);
            }
        }
        __syncthreads();
        suffix[t] = hist[t];
        __syncthreads();
        #pragma unroll
        for (int off = 1; off < 256; off <<= 1) {
            const int add = (t + off < 256) ? suffix[t + off] : 0;
            __syncthreads();
            suffix[t] += add;
            __syncthreads();
        }
        const int sfx = suffix[t];
        const int nxt = (t < 255) ? suffix[t + 1] : 0;
        if (sfx >= rem && nxt < rem) s_bin = t;
        __syncthreads();
        const int b = s_bin;
        const int above = (b < 255) ? suffix[b + 1] : 0;
        rem -= above;
        prefix = (prefix << 8) | (unsigned)b;
        __syncthreads();
    }

    // approx k-th value and boundary window
    const float vT = finv(prefix);
    const float dlt = 1e-3f;
    const float hiThr = vT + dlt;
    const float loThr = vT - dlt;

    if (t == 0) { c_hi_s = 0; n_c_s = 0; out_cnt = 0; }
    __syncthreads();

    // count sure-selected, collect boundary candidates
    #pragma unroll
    for (int i = 0; i < NVEC; ++i) {
        const float* vv = (const float*)&vals[i];
        #pragma unroll
        for (int j = 0; j < 4; ++j) {
            const float v = vv[j];
            if (v > hiThr) {
                atomicAdd(&c_hi_s, 1);
            } else if (v > loThr) {
                const int s = atomicAdd(&n_c_s, 1);
                if (s < 128) { cand_idx[s] = (t + 256 * i) * 4 + j; cand_sel[s] = 0; }
            }
        }
    }
    __syncthreads();

    const int n_c = min(n_c_s, 128);

    // exact fp32 recompute of each candidate's z_pre (one wave per candidate)
    {
        const int wv_id = t >> 6, ln = t & 63;
        const float* xr = x + (size_t)row * D;
        for (int c = wv_id; c < n_c; c += 4) {
            const int f = cand_idx[c];
            const float* wr = Wenc + (size_t)f * D;
            float s = 0.f;
            for (int d = ln * 4; d < D; d += 256) {
                float4 xv = *(const float4*)(xr + d);
                float4 bd = *(const float4*)(b_dec + d);
                float4 wv4 = *(const float4*)(wr + d);
                s = fmaf(xv.x - bd.x, wv4.x, s);
                s = fmaf(xv.y - bd.y, wv4.y, s);
                s = fmaf(xv.z - bd.z, wv4.z, s);
                s = fmaf(xv.w - bd.w, wv4.w, s);
            }
            #pragma unroll
            for (int o = 32; o > 0; o >>= 1) s += __shfl_down(s, o, 64);
            if (ln == 0) cand_val[c] = s + b_enc[f];
        }
    }
    __syncthreads();

    // select the remaining (k - c_hi) among candidates by (val desc, idx asc)
    if (t == 0) {
        int need = k - c_hi_s;
        if (need > n_c) need = n_c;
        for (int it = 0; it < need; ++it) {
            int bi = -1; float bv = 0.f;
            for (int c = 0; c < n_c; ++c) {
                if (cand_sel[c]) continue;
                const float v = cand_val[c];
                if (bi < 0 || v > bv || (v == bv && cand_idx[c] < cand_idx[bi])) {
                    bi = c; bv = v;
                }
            }
            if (bi < 0) break;
            cand_sel[bi] = 1;
        }
    }
    __syncthreads();

    // final write: dense z + compact (val, idx) list
    float4* dstz = (float4*)(z + (size_t)row * F);
    float*  wv   = ws_vals + (size_t)row * MAXK;
    int*    wi   = ws_idx  + (size_t)row * MAXK;

    #pragma unroll
    for (int i = 0; i < NVEC; ++i) {
        const int p4 = t + 256 * i;
        if (p4 < nv4) {
            const float* vv = (const float*)&vals[i];
            float4 outv;
            float* ov = (float*)&outv;
            #pragma unroll
            for (int j = 0; j < 4; ++j) {
                const int pos = p4 * 4 + j;
                const float v = vv[j];
                float zv = 0.f;
                bool sel = false;
                if (v > hiThr) {
                    zv = fmaxf(v, 0.f); sel = true;
                } else if (v > loThr) {
                    for (int c = 0; c < n_c; ++c) {
                        if (cand_idx[c] == pos) {
                            if (cand_sel[c]) { zv = fmaxf(cand_val[c], 0.f); sel = true; }
                            break;
                        }
                    }
                }
                ov[j] = zv;
                if (sel) {
                    const int s = atomicAdd(&out_cnt, 1);
                    if (s < MAXK) { wv[s] = zv; wi[s] = pos; }
                }
            }
            dstz[p4] = outv;
        }
    }
}

// ---------------------------------------------------------------------------
// Transpose W_dec [D, F] -> W_decT [F, D]
// ---------------------------------------------------------------------------
__global__ __launch_bounds__(256)
void transpose_kernel(const float* __restrict__ in, float* __restrict__ out,
                      int R, int C)
{
    __shared__ float tile[32][33];
    const int c0 = blockIdx.x * 32;
    const int r0 = blockIdx.y * 32;
    const int tx = threadIdx.x & 31;
    const int ty = threadIdx.x >> 5;

    #pragma unroll
    for (int i = ty; i < 32; i += 8) {
        const int r = r0 + i, c = c0 + tx;
        tile[i][tx] = (r < R && c < C) ? in[(size_t)r * C + c] : 0.f;
    }
    __syncthreads();
    #pragma unroll
    for (int i = ty; i < 32; i += 8) {
        const int c = c0 + i, r = r0 + tx;
        if (c < C && r < R) out[(size_t)c * R + r] = tile[tx][i];
    }
}

// ---------------------------------------------------------------------------
// Sparse decode: x_hat[b,:] = b_dec + sum_j val_j * W_decT[idx_j,:]
// ---------------------------------------------------------------------------
__global__ __launch_bounds__(256)
void decode_kernel(const float* __restrict__ WdT, const float* __restrict__ wvals,
                   const int* __restrict__ widx, const float* __restrict__ b_dec,
                   float* __restrict__ x_hat, const int* __restrict__ k_ptr, int D)
{
    const int row = blockIdx.x;
    const int t   = threadIdx.x;
    int k = *k_ptr;
    if (k > MAXK) k = MAXK;

    const float* wv = wvals + (size_t)row * MAXK;
    const int*   wi = widx  + (size_t)row * MAXK;

    for (int d0 = t * 4; d0 < D; d0 += 1024) {
        float4 acc = *(const float4*)(b_dec + d0);
        for (int j = 0; j < k; ++j) {
            const float v = wv[j];
            const int   f = wi[j];
            const float4 w = *(const float4*)(WdT + (size_t)f * D + d0);
            acc.x = fmaf(v, w.x, acc.x);
            acc.y = fmaf(v, w.y, acc.y);
            acc.z = fmaf(v, w.z, acc.z);
            acc.w = fmaf(v, w.w, acc.w);
        }
        *(float4*)(x_hat + (size_t)row * D + d0) = acc;
    }
}

// ---------------------------------------------------------------------------
extern "C" void kernel_launch(void* const* d_in, const int* in_sizes, int n_in,
                              void* d_out, int out_size, void* d_ws, size_t ws_size,
                              hipStream_t stream)
{
    const float* x     = (const float*)d_in[0];
    const float* W_enc = (const float*)d_in[1];
    const float* b_enc = (const float*)d_in[2];
    const float* W_dec = (const float*)d_in[3];
    const float* b_dec = (const float*)d_in[4];
    const int*   k_ptr = (const int*)d_in[5];

    const int F = in_sizes[2];
    const int D = in_sizes[4];
    const int B = in_sizes[0] / D;

    float* x_hat = (float*)d_out;
    float* z     = x_hat + (size_t)B * D;
    float* z_pre = z + (size_t)B * F;

    float* WdT = (float*)d_ws;                     // F*D floats
    float* wv  = WdT + (size_t)F * D;              // B*MAXK
    int*   wi  = (int*)(wv + (size_t)B * MAXK);    // B*MAXK

    encode_gemm_bf16x3<<<dim3(F / 256, B / 128), 256, 0, stream>>>(
        x, W_enc, b_enc, b_dec, z_pre, D, F);

    transpose_kernel<<<dim3((F + 31) / 32, (D + 31) / 32), 256, 0, stream>>>(
        W_dec, WdT, D, F);

    const int nv4  = F / 4;
    const int nvec = (nv4 + 255) / 256;
    if (nvec <= 4)
        topk_kernel<4><<<B, 256, 0, stream>>>(z_pre, z, wv, wi, k_ptr, x, W_enc, b_enc, b_dec, F, D);
    else if (nvec <= 8)
        topk_kernel<8><<<B, 256, 0, stream>>>(z_pre, z, wv, wi, k_ptr, x, W_enc, b_enc, b_dec, F, D);
    else if (nvec <= 16)
        topk_kernel<16><<<B, 256, 0, stream>>>(z_pre, z, wv, wi, k_ptr, x, W_enc, b_enc, b_dec, F, D);
    else
        topk_kernel<32><<<B, 256, 0, stream>>>(z_pre, z, wv, wi, k_ptr, x, W_enc, b_enc, b_dec, F, D);

    decode_kernel<<<B, 256, 0, stream>>>(WdT, wv, wi, b_dec, x_hat, k_ptr, D);
}